// Round 4
// baseline (189.162 us; speedup 1.0000x reference)
//
#include <hip/hip_runtime.h>
#include <math.h>

#define N 2048
#define F 128
#define O 128
#define E 16

#define BN 32
#define BK 32
#define KC 8
#define MK (N / KC)        // 256
#define STEPS (MK / BK)    // 8
#define APAD 40            // u16 row stride, 80B -> ~2-way max (free)
#define BPAD 40

typedef __attribute__((ext_vector_type(8))) short          shortx8;
typedef __attribute__((ext_vector_type(8))) unsigned short u16x8;
typedef __attribute__((ext_vector_type(4))) float          floatx4;

static __device__ __forceinline__ unsigned short f2bf(float f) {
    unsigned int u = __float_as_uint(f);
    unsigned int r = (u + 0x7FFFu + ((u >> 16) & 1u)) >> 16;
    return (unsigned short)r;
}

// ---------------- Kernel 1: pre[b][n][o] = (x @ w_b)[n][o]  -> bf16 ----------------
__global__ __launch_bounds__(128)
void pre_gemm(const float* __restrict__ x,
              const float* __restrict__ w0,
              const float* __restrict__ w1,
              unsigned short* __restrict__ pre_bf) {
    const int n = blockIdx.x;
    const int b = blockIdx.y;
    const int o = threadIdx.x;
    const float* __restrict__ w = b ? w1 : w0;
    __shared__ float xs[F];
    xs[o] = x[(size_t)n * F + o];
    __syncthreads();
    float acc = 0.f;
#pragma unroll 8
    for (int k = 0; k < F; ++k)
        acc += xs[k] * w[(size_t)k * O + o];
    pre_bf[(size_t)b * N * O + (size_t)n * O + o] = f2bf(acc);
}

// ---------------- Kernel 2: preT[b][o][n] = pre[b][n][o]  (bf16 transpose) ----------
__global__ __launch_bounds__(256)
void transpose_pre(const unsigned short* __restrict__ pre_bf,
                   unsigned short* __restrict__ preT) {
    __shared__ unsigned short tile[64][65];
    const int n0 = blockIdx.x * 64, o0 = blockIdx.y * 64;
    const size_t base = (size_t)blockIdx.z * N * O;
    const int t = threadIdx.x;
    const int r = t >> 2, q = t & 3;
    const unsigned short* src = pre_bf + base + (size_t)(n0 + r) * O + o0 + q * 16;
    u16x8 v0 = *(const u16x8*)(src);
    u16x8 v1 = *(const u16x8*)(src + 8);
#pragma unroll
    for (int j = 0; j < 8; ++j) {
        tile[q * 16 + j][r]     = v0[j];
        tile[q * 16 + 8 + j][r] = v1[j];
    }
    __syncthreads();
    u16x8 w0v, w1v;
#pragma unroll
    for (int j = 0; j < 8; ++j) {
        w0v[j] = tile[r][q * 16 + j];
        w1v[j] = tile[r][q * 16 + 8 + j];
    }
    unsigned short* dst = preT + base + (size_t)(o0 + r) * N + n0 + q * 16;
    *(u16x8*)(dst)     = w0v;
    *(u16x8*)(dst + 8) = w1v;
}

// ---------------- Kernel 3: fused gate + dual-GEMM, coalesced gate loads ------------
// grid: 512 blocks = 64 rowblocks(BN=32) x 8 kchunks(MK=256); 512 threads (8 waves).
// Gate dot split across 4 lanes -> every ef/we wave load is 1KB contiguous.

__device__ __forceinline__ void mfma_step(
    const unsigned short* aS, const unsigned short* aG,
    const unsigned short* B0, const unsigned short* B1,
    int arow, int kg, int col0, floatx4& acc0, floatx4& acc1)
{
    const shortx8 a_s = *(const shortx8*)(aS + arow * APAD + kg * 8);
    const shortx8 a_g = *(const shortx8*)(aG + arow * APAD + kg * 8);
    const shortx8 b00 = *(const shortx8*)(B0 + col0 * BPAD + kg * 8);
    const shortx8 b10 = *(const shortx8*)(B1 + col0 * BPAD + kg * 8);
    const shortx8 b01 = *(const shortx8*)(B0 + (col0 + 16) * BPAD + kg * 8);
    const shortx8 b11 = *(const shortx8*)(B1 + (col0 + 16) * BPAD + kg * 8);
    acc0 = __builtin_amdgcn_mfma_f32_16x16x32_bf16(a_s, b00, acc0, 0, 0, 0);
    acc0 = __builtin_amdgcn_mfma_f32_16x16x32_bf16(a_g, b10, acc0, 0, 0, 0);
    acc1 = __builtin_amdgcn_mfma_f32_16x16x32_bf16(a_s, b01, acc1, 0, 0, 0);
    acc1 = __builtin_amdgcn_mfma_f32_16x16x32_bf16(a_g, b11, acc1, 0, 0, 0);
}

__global__ __launch_bounds__(512, 4)
void fused_gemm(const float* __restrict__ sup,
                const float* __restrict__ ef,
                const float* __restrict__ we,
                const float* __restrict__ be,
                const unsigned short* __restrict__ preT,
                float* __restrict__ partial) {
    __shared__ unsigned short aS0[BN * APAD], aG0[BN * APAD];
    __shared__ unsigned short B00[O * BPAD],  B10[O * BPAD];
    __shared__ unsigned short aS1[BN * APAD], aG1[BN * APAD];
    __shared__ unsigned short B01[O * BPAD],  B11[O * BPAD];

    const int t  = threadIdx.x;
    const int bx = blockIdx.x;
    const int rb = bx & 63;
    const int kc = bx >> 6;
    const int n0     = rb * BN;
    const int m_base = kc * MK;

    const float* __restrict__ S0   = sup;
    const float* __restrict__ sup1 = sup + (size_t)N * N;
    const float4* __restrict__ efv = (const float4*)ef;
    const float4* __restrict__ wev = (const float4*)we;

    const int lane = t & 63;
    const int wid  = t >> 6;       // 0..7
    const int wrow = wid >> 2;     // 0..1
    const int wcol = wid & 3;      // 0..3

    const int sub = t & 3;         // quarter-dot slot / B column slot
    const int grp = t >> 2;        // 0..127: pair group / B row

    const int arow = wrow * 16 + (lane & 15);
    const int kg   = lane >> 4;
    const int col0 = wcol * 32 + (lane & 15);

    floatx4 acc0 = {0.f, 0.f, 0.f, 0.f};
    floatx4 acc1 = {0.f, 0.f, 0.f, 0.f};

    auto produce = [&](int m0, unsigned short* aS, unsigned short* aG,
                       unsigned short* B0, unsigned short* B1) {
        // B tiles: preT[b][o=grp][m0 + sub*8 ..+8)  (contiguous 1KB per wave instr)
        {
            const size_t src = (size_t)grp * N + (size_t)(m0 + sub * 8);
            *(u16x8*)(B0 + grp * BPAD + sub * 8) = *(const u16x8*)(preT + src);
            *(u16x8*)(B1 + grp * BPAD + sub * 8) =
                *(const u16x8*)(preT + (size_t)O * N + src);
        }
        const size_t pbase = (size_t)n0 * N + (size_t)m0;
        // gate: 4 lanes per pair, contiguous float4 loads, quad shuffle reduce
#pragma unroll
        for (int r = 0; r < 8; ++r) {
            const int p  = r * 128 + grp;          // 0..1023
            const int nn = p >> 5, mm = p & 31;
            const size_t pix = pbase + (size_t)nn * N + mm;
            const float4 e = efv[pix * 4 + sub];
            const float4 w = wev[pix * 4 + sub];
            float v = e.x * w.x + e.y * w.y + e.z * w.z + e.w * w.w;
            v += __shfl_xor(v, 1);
            v += __shfl_xor(v, 2);
            const float g = (1.f / (1.f + __expf(-(v + be[pix])))) * sup1[pix];
            if (sub == 0) aG[nn * APAD + mm] = f2bf(g);
        }
        // S0 tile: coalesced
#pragma unroll
        for (int r = 0; r < 2; ++r) {
            const int p  = r * 512 + t;
            const int nn = p >> 5, mm = p & 31;
            aS[nn * APAD + mm] = f2bf(S0[pbase + (size_t)nn * N + mm]);
        }
    };

    produce(m_base, aS0, aG0, B00, B10);
    __syncthreads();

#pragma unroll 1
    for (int s = 0; s < STEPS; s += 2) {
        produce(m_base + (s + 1) * BK, aS1, aG1, B01, B11);
        mfma_step(aS0, aG0, B00, B10, arow, kg, col0, acc0, acc1);
        __syncthreads();
        if (s + 2 < STEPS)
            produce(m_base + (s + 2) * BK, aS0, aG0, B00, B10);
        mfma_step(aS1, aG1, B01, B11, arow, kg, col0, acc0, acc1);
        __syncthreads();
    }

    // C/D layout: col = lane&15, row = (lane>>4)*4 + j  (m89-verified)
    const int prow = (lane >> 4) * 4;
    const int pcol = wcol * 32 + (lane & 15);
    float* dst = partial + (size_t)kc * (N * O)
               + (size_t)(n0 + wrow * 16 + prow) * O + pcol;
#pragma unroll
    for (int j = 0; j < 4; ++j) {
        dst[(size_t)j * O]      = acc0[j];
        dst[(size_t)j * O + 16] = acc1[j];
    }
}

// ---------------- Kernel 4: out = relu(sum_kc partial + bias) -----------------------
__global__ __launch_bounds__(256)
void reduce_out(const float* __restrict__ partial,
                const float* __restrict__ bias,
                float* __restrict__ out) {
    const int i4 = blockIdx.x * 256 + threadIdx.x;   // 0..65535 (float4 index)
    const float4* p = (const float4*)partial;
    float4 r = p[i4];
#pragma unroll
    for (int j = 1; j < KC; ++j) {
        const float4 a = p[i4 + (size_t)j * 65536];
        r.x += a.x; r.y += a.y; r.z += a.z; r.w += a.w;
    }
    const float4 bb = ((const float4*)bias)[i4 & 31];
    float4 o;
    o.x = fmaxf(r.x + bb.x, 0.f);
    o.y = fmaxf(r.y + bb.y, 0.f);
    o.z = fmaxf(r.z + bb.z, 0.f);
    o.w = fmaxf(r.w + bb.w, 0.f);
    ((float4*)out)[i4] = o;
}

extern "C" void kernel_launch(void* const* d_in, const int* in_sizes, int n_in,
                              void* d_out, int out_size, void* d_ws, size_t ws_size,
                              hipStream_t stream) {
    const float* x   = (const float*)d_in[0];   // [N,F]
    const float* sup = (const float*)d_in[1];   // [2,N,N]
    const float* ef  = (const float*)d_in[2];   // [N,N,E]
    const float* we  = (const float*)d_in[3];   // [N,N,E]
    const float* be  = (const float*)d_in[4];   // [N,N]
    const float* w0  = (const float*)d_in[5];   // [F,O]
    const float* w1  = (const float*)d_in[6];   // [F,O]
    const float* b   = (const float*)d_in[7];   // [O]
    float* out = (float*)d_out;

    unsigned short* pre_bf = (unsigned short*)d_ws;       // [2][N][O] bf16, 1 MB
    unsigned short* preT   = pre_bf + 2 * (size_t)N * O;  // [2][O][N] bf16, 1 MB
    float* partial = (float*)(preT + 2 * (size_t)N * O);  // [KC][N][O] f32, 8 MB

    pre_gemm<<<dim3(N, 2), 128, 0, stream>>>(x, w0, w1, pre_bf);
    transpose_pre<<<dim3(N / 64, O / 64, 2), 256, 0, stream>>>(pre_bf, preT);
    fused_gemm<<<KC * 64, 512, 0, stream>>>(sup, ef, we, be, preT, partial);
    reduce_out<<<256, 256, 0, stream>>>(partial, b, out);
}

// Round 5
// 143.264 us; speedup vs baseline: 1.3204x; 1.3204x over previous
//
#include <hip/hip_runtime.h>
#include <math.h>

#define N 2048
#define F 128
#define O 128
#define E 16

#define BK 32
#define GBN 16             // GEMM rows per block
#define GKC 8              // split-K chunks
#define GMK (N / GKC)      // 256 K per chunk
#define GSTEPS (GMK / BK)  // 8

typedef __attribute__((ext_vector_type(8))) short          shortx8;
typedef __attribute__((ext_vector_type(8))) unsigned short u16x8;
typedef __attribute__((ext_vector_type(4))) float          floatx4;

static __device__ __forceinline__ unsigned short f2bf(float f) {
    unsigned int u = __float_as_uint(f);
    unsigned int r = (u + 0x7FFFu + ((u >> 16) & 1u)) >> 16;
    return (unsigned short)r;
}

// ---------------- Kernel 1: pre[b][n][o] = (x @ w_b)[n][o]  -> bf16 ----------------
__global__ __launch_bounds__(128)
void pre_gemm(const float* __restrict__ x,
              const float* __restrict__ w0,
              const float* __restrict__ w1,
              unsigned short* __restrict__ pre_bf) {
    const int n = blockIdx.x;
    const int b = blockIdx.y;
    const int o = threadIdx.x;
    const float* __restrict__ w = b ? w1 : w0;
    __shared__ float xs[F];
    xs[o] = x[(size_t)n * F + o];
    __syncthreads();
    float acc = 0.f;
#pragma unroll 8
    for (int k = 0; k < F; ++k)
        acc += xs[k] * w[(size_t)k * O + o];
    pre_bf[(size_t)b * N * O + (size_t)n * O + o] = f2bf(acc);
}

// ---------------- Kernel 2: preT[b][o][n] = pre[b][n][o]  (bf16 transpose) ----------
__global__ __launch_bounds__(256)
void transpose_pre(const unsigned short* __restrict__ pre_bf,
                   unsigned short* __restrict__ preT) {
    __shared__ unsigned short tile[64][65];
    const int n0 = blockIdx.x * 64, o0 = blockIdx.y * 64;
    const size_t base = (size_t)blockIdx.z * N * O;
    const int t = threadIdx.x;
    const int r = t >> 2, q = t & 3;
    const unsigned short* src = pre_bf + base + (size_t)(n0 + r) * O + o0 + q * 16;
    u16x8 v0 = *(const u16x8*)(src);
    u16x8 v1 = *(const u16x8*)(src + 8);
#pragma unroll
    for (int j = 0; j < 8; ++j) {
        tile[q * 16 + j][r]     = v0[j];
        tile[q * 16 + 8 + j][r] = v1[j];
    }
    __syncthreads();
    u16x8 w0v, w1v;
#pragma unroll
    for (int j = 0; j < 8; ++j) {
        w0v[j] = tile[r][q * 16 + j];
        w1v[j] = tile[r][q * 16 + 8 + j];
    }
    unsigned short* dst = preT + base + (size_t)(o0 + r) * N + n0 + q * 16;
    *(u16x8*)(dst)     = w0v;
    *(u16x8*)(dst + 8) = w1v;
}

// ---------------- Kernel 3: gate (pure streaming, R1-proven form) -------------------
// G[n,m] = bf16( sigmoid(dot16(ef,we) + be) * sup1 );  4 lanes per pair.
__global__ __launch_bounds__(256)
void gate_kernel(const float* __restrict__ ef,
                 const float* __restrict__ we,
                 const float* __restrict__ be,
                 const float* __restrict__ sup1,
                 unsigned short* __restrict__ G) {
    const size_t tid  = (size_t)blockIdx.x * 256 + threadIdx.x;
    const size_t pair = tid >> 2;
    const int    sub  = (int)(threadIdx.x & 3);
    const float4 e4 = ((const float4*)ef)[pair * 4 + sub];
    const float4 w4 = ((const float4*)we)[pair * 4 + sub];
    float v = e4.x * w4.x + e4.y * w4.y + e4.z * w4.z + e4.w * w4.w;
    v += __shfl_xor(v, 1);
    v += __shfl_xor(v, 2);
    if (sub == 0) {
        const float t = v + be[pair];
        const float g = (1.f / (1.f + __expf(-t))) * sup1[pair];
        G[pair] = f2bf(g);
    }
}

// ---------------- Kernel 4: barrier-free dual GEMM (split-K, MFMA) ------------------
// partial[kc][n][o] = sum_{m in chunk} S0[n,m]*pre0[m,o] + G[n,m]*pre1[m,o]
// No LDS, no __syncthreads: each wave owns a 16-row x (2x16)-col tile.
__global__ __launch_bounds__(256)
void dual_gemm(const float* __restrict__ S0,
               const unsigned short* __restrict__ G,
               const unsigned short* __restrict__ preT,
               float* __restrict__ partial) {
    const int t    = threadIdx.x;
    const int lane = t & 63;
    const int w    = t >> 6;                 // 0..3: column group
    const int rb   = blockIdx.x & 127;       // row block
    const int kc   = blockIdx.x >> 7;        // K chunk
    const int n0   = rb * GBN;
    const int m_b  = kc * GMK;

    const int row  = lane & 15;              // A row / B col within 16
    const int kg   = lane >> 4;              // 0..3: K subgroup (8 elems)
    const int col0 = w * 32 + row;

    const float*          aS = S0   + (size_t)(n0 + row) * N + m_b + kg * 8;
    const unsigned short* aG = G    + (size_t)(n0 + row) * N + m_b + kg * 8;
    const unsigned short* b0 = preT + (size_t)col0 * N            + m_b + kg * 8;
    const unsigned short* b1 = b0   + (size_t)16 * N;
    const unsigned short* c0 = b0   + (size_t)O * N;   // preT[1]
    const unsigned short* c1 = b1   + (size_t)O * N;

    floatx4 acc0 = {0.f, 0.f, 0.f, 0.f};
    floatx4 acc1 = {0.f, 0.f, 0.f, 0.f};

#pragma unroll 2
    for (int s = 0; s < GSTEPS; ++s) {
        const int mo = s * BK;
        const float4 f0 = *(const float4*)(aS + mo);
        const float4 f1 = *(const float4*)(aS + mo + 4);
        const shortx8 a_g = *(const shortx8*)(aG + mo);
        const shortx8 b00 = *(const shortx8*)(b0 + mo);
        const shortx8 b01 = *(const shortx8*)(b1 + mo);
        const shortx8 b10 = *(const shortx8*)(c0 + mo);
        const shortx8 b11 = *(const shortx8*)(c1 + mo);
        shortx8 a_s;
        a_s[0] = (short)f2bf(f0.x); a_s[1] = (short)f2bf(f0.y);
        a_s[2] = (short)f2bf(f0.z); a_s[3] = (short)f2bf(f0.w);
        a_s[4] = (short)f2bf(f1.x); a_s[5] = (short)f2bf(f1.y);
        a_s[6] = (short)f2bf(f1.z); a_s[7] = (short)f2bf(f1.w);
        acc0 = __builtin_amdgcn_mfma_f32_16x16x32_bf16(a_s, b00, acc0, 0, 0, 0);
        acc0 = __builtin_amdgcn_mfma_f32_16x16x32_bf16(a_g, b10, acc0, 0, 0, 0);
        acc1 = __builtin_amdgcn_mfma_f32_16x16x32_bf16(a_s, b01, acc1, 0, 0, 0);
        acc1 = __builtin_amdgcn_mfma_f32_16x16x32_bf16(a_g, b11, acc1, 0, 0, 0);
    }

    // C/D layout: col = lane&15, row = (lane>>4)*4 + j  (m89-verified)
    float* dst = partial + (size_t)kc * (N * O)
               + (size_t)(n0 + kg * 4) * O + w * 32 + row;
#pragma unroll
    for (int j = 0; j < 4; ++j) {
        dst[(size_t)j * O]      = acc0[j];
        dst[(size_t)j * O + 16] = acc1[j];
    }
}

// ---------------- Kernel 5: out = relu(sum_kc partial + bias) -----------------------
__global__ __launch_bounds__(256)
void reduce_out(const float* __restrict__ partial,
                const float* __restrict__ bias,
                float* __restrict__ out) {
    const int i4 = blockIdx.x * 256 + threadIdx.x;   // float4 index over [N][O]
    const float4* p = (const float4*)partial;
    float4 r = p[i4];
#pragma unroll
    for (int j = 1; j < GKC; ++j) {
        const float4 a = p[i4 + (size_t)j * (N * O / 4)];
        r.x += a.x; r.y += a.y; r.z += a.z; r.w += a.w;
    }
    const float4 bb = ((const float4*)bias)[i4 & (O / 4 - 1)];
    float4 o;
    o.x = fmaxf(r.x + bb.x, 0.f);
    o.y = fmaxf(r.y + bb.y, 0.f);
    o.z = fmaxf(r.z + bb.z, 0.f);
    o.w = fmaxf(r.w + bb.w, 0.f);
    ((float4*)out)[i4] = o;
}

extern "C" void kernel_launch(void* const* d_in, const int* in_sizes, int n_in,
                              void* d_out, int out_size, void* d_ws, size_t ws_size,
                              hipStream_t stream) {
    const float* x   = (const float*)d_in[0];   // [N,F]
    const float* sup = (const float*)d_in[1];   // [2,N,N]
    const float* ef  = (const float*)d_in[2];   // [N,N,E]
    const float* we  = (const float*)d_in[3];   // [N,N,E]
    const float* be  = (const float*)d_in[4];   // [N,N]
    const float* w0  = (const float*)d_in[5];   // [F,O]
    const float* w1  = (const float*)d_in[6];   // [F,O]
    const float* b   = (const float*)d_in[7];   // [O]
    float* out = (float*)d_out;

    // workspace layout (17.4 MB total; pre_bf aliased into partial region):
    unsigned short* preT   = (unsigned short*)d_ws;           // [2][O][N] bf16, 1 MB
    unsigned short* G      = preT + 2 * (size_t)N * O;        // [N][N]   bf16, 8.4 MB
    float*          partial = (float*)(G + (size_t)N * N);    // [GKC][N][O] f32, 8 MB
    unsigned short* pre_bf = (unsigned short*)partial;        // [2][N][O] bf16 (temp)

    pre_gemm<<<dim3(N, 2), 128, 0, stream>>>(x, w0, w1, pre_bf);
    transpose_pre<<<dim3(N / 64, O / 64, 2), 256, 0, stream>>>(pre_bf, preT);
    // pre_bf dead from here; partial region reused by dual_gemm.
    gate_kernel<<<(unsigned)((size_t)N * N * 4 / 256), 256, 0, stream>>>(
        ef, we, be, sup + (size_t)N * N, G);
    dual_gemm<<<GKC * 128, 256, 0, stream>>>(sup, G, preT, partial);
    reduce_out<<<N * O / 4 / 256, 256, 0, stream>>>(partial, b, out);
}

// Round 6
// 138.074 us; speedup vs baseline: 1.3700x; 1.0376x over previous
//
#include <hip/hip_runtime.h>
#include <math.h>

#define N 2048
#define F 128
#define O 128
#define E 16

typedef __attribute__((ext_vector_type(8))) short          shortx8;
typedef __attribute__((ext_vector_type(8))) unsigned short u16x8;
typedef __attribute__((ext_vector_type(4))) unsigned short u16x4;
typedef __attribute__((ext_vector_type(4))) float          floatx4;

static __device__ __forceinline__ unsigned short f2bf(float f) {
    unsigned int u = __float_as_uint(f);
    unsigned int r = (u + 0x7FFFu + ((u >> 16) & 1u)) >> 16;
    return (unsigned short)r;
}

// ---------------- Kernel 1: preT[b][o][n] = (x @ w_b)[n][o] via MFMA ----------------
// grid (128, 2), 256 thr. Block: 16 rows of x, all 128 cols, mat b.
__global__ __launch_bounds__(256)
void pre_t(const float* __restrict__ x,
           const float* __restrict__ w0,
           const float* __restrict__ w1,
           unsigned short* __restrict__ preT) {
    __shared__ unsigned short wT[128 * 136];   // w^T bf16, padded stride 136
    const int t  = threadIdx.x;
    const int n0 = blockIdx.x * 16;
    const int b  = blockIdx.y;
    const float* __restrict__ wsrc = b ? w1 : w0;

#pragma unroll
    for (int i = 0; i < 64; ++i) {
        const int idx = i * 256 + t;          // coalesced read of w[k][o]
        const int k = idx >> 7, o = idx & 127;
        wT[o * 136 + k] = f2bf(wsrc[idx]);
    }
    __syncthreads();

    const int lane = t & 63;
    const int wv   = t >> 6;        // 0..3: 32-col group
    const int row  = lane & 15;
    const int kg   = lane >> 4;
    const int col0 = wv * 32 + row;

    floatx4 acc0 = {0.f, 0.f, 0.f, 0.f};
    floatx4 acc1 = {0.f, 0.f, 0.f, 0.f};

#pragma unroll
    for (int kk = 0; kk < 4; ++kk) {
        const float* xp = x + (size_t)(n0 + row) * F + kk * 32 + kg * 8;
        const float4 f0 = *(const float4*)(xp);
        const float4 f1 = *(const float4*)(xp + 4);
        shortx8 a;
        a[0] = (short)f2bf(f0.x); a[1] = (short)f2bf(f0.y);
        a[2] = (short)f2bf(f0.z); a[3] = (short)f2bf(f0.w);
        a[4] = (short)f2bf(f1.x); a[5] = (short)f2bf(f1.y);
        a[6] = (short)f2bf(f1.z); a[7] = (short)f2bf(f1.w);
        const shortx8 bA = *(const shortx8*)(wT + col0 * 136 + kk * 32 + kg * 8);
        const shortx8 bB = *(const shortx8*)(wT + (col0 + 16) * 136 + kk * 32 + kg * 8);
        acc0 = __builtin_amdgcn_mfma_f32_16x16x32_bf16(a, bA, acc0, 0, 0, 0);
        acc1 = __builtin_amdgcn_mfma_f32_16x16x32_bf16(a, bB, acc1, 0, 0, 0);
    }

    // C/D: col = lane&15, row = kg*4 + j  -> preT[b][col][n0+row+j], j consecutive
    const int prow = kg * 4;
    u16x4 s0, s1;
#pragma unroll
    for (int j = 0; j < 4; ++j) { s0[j] = f2bf(acc0[j]); s1[j] = f2bf(acc1[j]); }
    *(u16x4*)(preT + ((size_t)b * O + col0) * N + n0 + prow)      = s0;
    *(u16x4*)(preT + ((size_t)b * O + col0 + 16) * N + n0 + prow) = s1;
}

// ---------------- Kernel 2: gate (pure streaming, R1/R5-proven form) ----------------
__global__ __launch_bounds__(256)
void gate_kernel(const float* __restrict__ ef,
                 const float* __restrict__ we,
                 const float* __restrict__ be,
                 const float* __restrict__ sup1,
                 unsigned short* __restrict__ G) {
    const size_t tid  = (size_t)blockIdx.x * 256 + threadIdx.x;
    const size_t pair = tid >> 2;
    const int    sub  = (int)(threadIdx.x & 3);
    const float4 e4 = ((const float4*)ef)[pair * 4 + sub];
    const float4 w4 = ((const float4*)we)[pair * 4 + sub];
    float v = e4.x * w4.x + e4.y * w4.y + e4.z * w4.z + e4.w * w4.w;
    v += __shfl_xor(v, 1);
    v += __shfl_xor(v, 2);
    if (sub == 0) {
        const float t = v + be[pair];
        const float g = (1.f / (1.f + __expf(-t))) * sup1[pair];
        G[pair] = f2bf(g);
    }
}

// ---------------- Kernel 3: dual GEMM, in-block split-K, direct output --------------
// grid 512 (XCD-swizzled), 256 thr / 4 waves. Block owns 16 rows x 32 cols;
// wave wv does K-range [wv*512, wv*512+512); LDS reduce; + bias, relu, write out.
__global__ __launch_bounds__(256)
void gemm_direct(const float* __restrict__ S0,
                 const unsigned short* __restrict__ G,
                 const unsigned short* __restrict__ preT,
                 const float* __restrict__ bias,
                 float* __restrict__ out) {
    __shared__ float red[4][16][36];

    const int bx   = blockIdx.x;
    const int orig = (bx & 7) * 64 + (bx >> 3);  // group 4 col-blocks per XCD
    const int rb   = orig >> 2;                  // 0..127
    const int cg   = orig & 3;                   // 0..3
    const int n0   = rb * 16;

    const int t    = threadIdx.x;
    const int lane = t & 63;
    const int wv   = t >> 6;
    const int m_b  = wv * 512;
    const int row  = lane & 15;
    const int kg   = lane >> 4;
    const int col0 = cg * 32 + row;

    const float*          aS = S0   + (size_t)(n0 + row) * N + m_b + kg * 8;
    const unsigned short* aG = G    + (size_t)(n0 + row) * N + m_b + kg * 8;
    const unsigned short* b0 = preT + (size_t)col0 * N        + m_b + kg * 8;
    const unsigned short* b1 = b0 + (size_t)16 * N;
    const unsigned short* c0 = b0 + (size_t)O * N;   // preT[1]
    const unsigned short* c1 = b1 + (size_t)O * N;

    floatx4 acc0 = {0.f, 0.f, 0.f, 0.f};
    floatx4 acc1 = {0.f, 0.f, 0.f, 0.f};

#pragma unroll 2
    for (int s = 0; s < 16; ++s) {
        const int mo = s * 32;
        const float4 f0 = *(const float4*)(aS + mo);
        const float4 f1 = *(const float4*)(aS + mo + 4);
        const shortx8 a_g = *(const shortx8*)(aG + mo);
        const shortx8 b00 = *(const shortx8*)(b0 + mo);
        const shortx8 b01 = *(const shortx8*)(b1 + mo);
        const shortx8 b10 = *(const shortx8*)(c0 + mo);
        const shortx8 b11 = *(const shortx8*)(c1 + mo);
        shortx8 a_s;
        a_s[0] = (short)f2bf(f0.x); a_s[1] = (short)f2bf(f0.y);
        a_s[2] = (short)f2bf(f0.z); a_s[3] = (short)f2bf(f0.w);
        a_s[4] = (short)f2bf(f1.x); a_s[5] = (short)f2bf(f1.y);
        a_s[6] = (short)f2bf(f1.z); a_s[7] = (short)f2bf(f1.w);
        acc0 = __builtin_amdgcn_mfma_f32_16x16x32_bf16(a_s, b00, acc0, 0, 0, 0);
        acc0 = __builtin_amdgcn_mfma_f32_16x16x32_bf16(a_g, b10, acc0, 0, 0, 0);
        acc1 = __builtin_amdgcn_mfma_f32_16x16x32_bf16(a_s, b01, acc1, 0, 0, 0);
        acc1 = __builtin_amdgcn_mfma_f32_16x16x32_bf16(a_g, b11, acc1, 0, 0, 0);
    }

    // stash per-wave acc in LDS: C/D col = lane&15, row = kg*4 + j
    const int prow = kg * 4;
#pragma unroll
    for (int j = 0; j < 4; ++j) {
        red[wv][prow + j][row]      = acc0[j];
        red[wv][prow + j][16 + row] = acc1[j];
    }
    __syncthreads();

    // each thread: one row r, two cols c,c+1
    const int r = t >> 4;
    const int c = (t & 15) * 2;
    float v0 = red[0][r][c]     + red[1][r][c]     + red[2][r][c]     + red[3][r][c];
    float v1 = red[0][r][c + 1] + red[1][r][c + 1] + red[2][r][c + 1] + red[3][r][c + 1];
    v0 = fmaxf(v0 + bias[cg * 32 + c],     0.f);
    v1 = fmaxf(v1 + bias[cg * 32 + c + 1], 0.f);
    float2 o2; o2.x = v0; o2.y = v1;
    *(float2*)(out + (size_t)(n0 + r) * O + cg * 32 + c) = o2;
}

extern "C" void kernel_launch(void* const* d_in, const int* in_sizes, int n_in,
                              void* d_out, int out_size, void* d_ws, size_t ws_size,
                              hipStream_t stream) {
    const float* x   = (const float*)d_in[0];   // [N,F]
    const float* sup = (const float*)d_in[1];   // [2,N,N]
    const float* ef  = (const float*)d_in[2];   // [N,N,E]
    const float* we  = (const float*)d_in[3];   // [N,N,E]
    const float* be  = (const float*)d_in[4];   // [N,N]
    const float* w0  = (const float*)d_in[5];   // [F,O]
    const float* w1  = (const float*)d_in[6];   // [F,O]
    const float* b   = (const float*)d_in[7];   // [O]
    float* out = (float*)d_out;

    unsigned short* preT = (unsigned short*)d_ws;   // [2][O][N] bf16, 1 MB
    unsigned short* G    = preT + 2 * (size_t)N * O; // [N][N]   bf16, 8.4 MB

    pre_t<<<dim3(N / 16, 2), 256, 0, stream>>>(x, w0, w1, preT);
    gate_kernel<<<(unsigned)((size_t)N * N * 4 / 256), 256, 0, stream>>>(
        ef, we, be, sup + (size_t)N * N, G);
    gemm_direct<<<512, 256, 0, stream>>>(sup, G, preT, b, out);
}